// Round 1
// baseline (61.292 us; speedup 1.0000x reference)
//
#include <hip/hip_runtime.h>

#define HRES 1024
#define WRES 1024
#define HF   128
#define WF   128
#define NOFF 6
#define CCH  512
#define BB   4
#define CHUNK 32

// ---------------------------------------------------------------------------
// Kernel A: low-res evidence, one thread per (b, k, i, j).
// E[b,k,i,j] = sum_{r,c in 3x3} smap[b, 8i+3+floor(dy)+r, 8j+3+floor(dx)+c]
//              * wy[r] * wx[c],  wx = [0.5(1-fx), 0.5, 0.5 fx] etc., zero-pad.
// ---------------------------------------------------------------------------
__global__ void evidence_kernel(const float* __restrict__ smap,
                                const float* __restrict__ sdir,
                                float* __restrict__ E) {
    int t = blockIdx.x * blockDim.x + threadIdx.x;
    if (t >= BB * NOFF * HF * WF) return;
    int j = t & (WF - 1);
    int i = (t >> 7) & (HF - 1);
    int k = (t >> 14) % NOFF;
    int b = t / (NOFF << 14);

    const float offs[NOFF] = {12.f, 20.f, 30.f, 42.f, 55.f, 67.f};
    float dirx = sdir[b * 2 + 0];
    float diry = sdir[b * 2 + 1];
    float d  = offs[k];
    float dx = dirx * d;
    float dy = -diry * d;
    float fxf = floorf(dx), fyf = floorf(dy);
    float wx = dx - fxf,    wy = dy - fyf;

    int X0 = 8 * j + 3 + (int)fxf;
    int Y0 = 8 * i + 3 + (int)fyf;

    float wxv[3] = {0.5f * (1.f - wx), 0.5f, 0.5f * wx};
    float wyv[3] = {0.5f * (1.f - wy), 0.5f, 0.5f * wy};

    const float* img = smap + (size_t)b * HRES * WRES;
    float acc = 0.f;
#pragma unroll
    for (int r = 0; r < 3; ++r) {
        int y = Y0 + r;
        if ((unsigned)y < HRES) {
            float rowacc = 0.f;
#pragma unroll
            for (int c = 0; c < 3; ++c) {
                int x = X0 + c;
                float v = ((unsigned)x < WRES) ? img[(size_t)y * WRES + x] : 0.f;
                rowacc += v * wxv[c];
            }
            acc += rowacc * wyv[r];
        }
    }
    E[t] = acc;
}

// ---------------------------------------------------------------------------
// Kernel B: out[b,c,h,w] = rgb[b,c,h,w] + gate*(sum_k E[b,k,h,w]*w[c,k] + bias[c])
// Block: 256 threads, each owns 4 consecutive pixels (float4). Block covers
// 1024 pixels of one batch, and a CHUNK of channels (grid.y).
// ---------------------------------------------------------------------------
__global__ __launch_bounds__(256) void mix_kernel(
        const float* __restrict__ rgb,
        const float* __restrict__ E,
        const float* __restrict__ w_conv,
        const float* __restrict__ b_conv,
        const float* __restrict__ gate,
        float* __restrict__ out) {
    __shared__ float s_w[CHUNK * NOFF];
    __shared__ float s_b[CHUNK];

    int tile = blockIdx.x;            // 0 .. B*16-1
    int b    = tile >> 4;
    int p    = (tile & 15) * 1024 + threadIdx.x * 4;   // pixel offset in hw-flat
    int c0   = blockIdx.y * CHUNK;
    float g  = gate[0];

    for (int idx = threadIdx.x; idx < CHUNK * NOFF; idx += blockDim.x)
        s_w[idx] = g * w_conv[(size_t)(c0 + idx / NOFF) * NOFF + idx % NOFF];
    for (int idx = threadIdx.x; idx < CHUNK; idx += blockDim.x)
        s_b[idx] = g * b_conv[c0 + idx];
    __syncthreads();

    float4 e[NOFF];
#pragma unroll
    for (int k = 0; k < NOFF; ++k)
        e[k] = *reinterpret_cast<const float4*>(
            E + (((size_t)(b * NOFF + k)) << 14) + p);

    const float4* rgbp = reinterpret_cast<const float4*>(
        rgb + (((size_t)(b * CCH + c0)) << 14) + p);
    float4* outp = reinterpret_cast<float4*>(
        out + (((size_t)(b * CCH + c0)) << 14) + p);
    const int stride4 = (1 << 14) / 4;   // channel stride in float4 units

#pragma unroll 4
    for (int c = 0; c < CHUNK; ++c) {
        float w0 = s_w[c * NOFF + 0], w1 = s_w[c * NOFF + 1];
        float w2 = s_w[c * NOFF + 2], w3 = s_w[c * NOFF + 3];
        float w4 = s_w[c * NOFF + 4], w5 = s_w[c * NOFF + 5];
        float bb = s_b[c];
        float4 r = rgbp[(size_t)c * stride4];
        float4 o;
        o.x = r.x + bb + e[0].x * w0 + e[1].x * w1 + e[2].x * w2
                       + e[3].x * w3 + e[4].x * w4 + e[5].x * w5;
        o.y = r.y + bb + e[0].y * w0 + e[1].y * w1 + e[2].y * w2
                       + e[3].y * w3 + e[4].y * w4 + e[5].y * w5;
        o.z = r.z + bb + e[0].z * w0 + e[1].z * w1 + e[2].z * w2
                       + e[3].z * w3 + e[4].z * w4 + e[5].z * w5;
        o.w = r.w + bb + e[0].w * w0 + e[1].w * w1 + e[2].w * w2
                       + e[3].w * w3 + e[4].w * w4 + e[5].w * w5;
        outp[(size_t)c * stride4] = o;
    }
}

// ---------------------------------------------------------------------------
// Fallback (only if workspace is unexpectedly tiny): fuse evidence inline.
// ---------------------------------------------------------------------------
__device__ float evidence_at(const float* __restrict__ img,
                             float dx, float dy, int i, int j) {
    float fxf = floorf(dx), fyf = floorf(dy);
    float wx = dx - fxf, wy = dy - fyf;
    int X0 = 8 * j + 3 + (int)fxf;
    int Y0 = 8 * i + 3 + (int)fyf;
    float wxv[3] = {0.5f * (1.f - wx), 0.5f, 0.5f * wx};
    float wyv[3] = {0.5f * (1.f - wy), 0.5f, 0.5f * wy};
    float acc = 0.f;
#pragma unroll
    for (int r = 0; r < 3; ++r) {
        int y = Y0 + r;
        if ((unsigned)y < HRES) {
            float rowacc = 0.f;
#pragma unroll
            for (int c = 0; c < 3; ++c) {
                int x = X0 + c;
                float v = ((unsigned)x < WRES) ? img[(size_t)y * WRES + x] : 0.f;
                rowacc += v * wxv[c];
            }
            acc += rowacc * wyv[r];
        }
    }
    return acc;
}

__global__ __launch_bounds__(256) void mix_fused_kernel(
        const float* __restrict__ rgb,
        const float* __restrict__ smap,
        const float* __restrict__ sdir,
        const float* __restrict__ w_conv,
        const float* __restrict__ b_conv,
        const float* __restrict__ gate,
        float* __restrict__ out) {
    __shared__ float s_w[CHUNK * NOFF];
    __shared__ float s_b[CHUNK];

    int tile = blockIdx.x;
    int b    = tile >> 4;
    int p    = (tile & 15) * 1024 + threadIdx.x * 4;
    int c0   = blockIdx.y * CHUNK;
    float g  = gate[0];

    for (int idx = threadIdx.x; idx < CHUNK * NOFF; idx += blockDim.x)
        s_w[idx] = g * w_conv[(size_t)(c0 + idx / NOFF) * NOFF + idx % NOFF];
    for (int idx = threadIdx.x; idx < CHUNK; idx += blockDim.x)
        s_b[idx] = g * b_conv[c0 + idx];
    __syncthreads();

    const float offs[NOFF] = {12.f, 20.f, 30.f, 42.f, 55.f, 67.f};
    float dirx = sdir[b * 2 + 0];
    float diry = sdir[b * 2 + 1];
    const float* img = smap + (size_t)b * HRES * WRES;
    int i  = p >> 7;
    int j0 = p & (WF - 1);

    float4 e[NOFF];
#pragma unroll
    for (int k = 0; k < NOFF; ++k) {
        float dx = dirx * offs[k];
        float dy = -diry * offs[k];
        e[k].x = evidence_at(img, dx, dy, i, j0 + 0);
        e[k].y = evidence_at(img, dx, dy, i, j0 + 1);
        e[k].z = evidence_at(img, dx, dy, i, j0 + 2);
        e[k].w = evidence_at(img, dx, dy, i, j0 + 3);
    }

    const float4* rgbp = reinterpret_cast<const float4*>(
        rgb + (((size_t)(b * CCH + c0)) << 14) + p);
    float4* outp = reinterpret_cast<float4*>(
        out + (((size_t)(b * CCH + c0)) << 14) + p);
    const int stride4 = (1 << 14) / 4;

#pragma unroll 4
    for (int c = 0; c < CHUNK; ++c) {
        float w0 = s_w[c * NOFF + 0], w1 = s_w[c * NOFF + 1];
        float w2 = s_w[c * NOFF + 2], w3 = s_w[c * NOFF + 3];
        float w4 = s_w[c * NOFF + 4], w5 = s_w[c * NOFF + 5];
        float bb = s_b[c];
        float4 r = rgbp[(size_t)c * stride4];
        float4 o;
        o.x = r.x + bb + e[0].x * w0 + e[1].x * w1 + e[2].x * w2
                       + e[3].x * w3 + e[4].x * w4 + e[5].x * w5;
        o.y = r.y + bb + e[0].y * w0 + e[1].y * w1 + e[2].y * w2
                       + e[3].y * w3 + e[4].y * w4 + e[5].y * w5;
        o.z = r.z + bb + e[0].z * w0 + e[1].z * w1 + e[2].z * w2
                       + e[3].z * w3 + e[4].z * w4 + e[5].z * w5;
        o.w = r.w + bb + e[0].w * w0 + e[1].w * w1 + e[2].w * w2
                       + e[3].w * w3 + e[4].w * w4 + e[5].w * w5;
        outp[(size_t)c * stride4] = o;
    }
}

extern "C" void kernel_launch(void* const* d_in, const int* in_sizes, int n_in,
                              void* d_out, int out_size, void* d_ws, size_t ws_size,
                              hipStream_t stream) {
    const float* rgb    = (const float*)d_in[0];
    const float* smap   = (const float*)d_in[1];
    const float* sdir   = (const float*)d_in[2];
    const float* w_conv = (const float*)d_in[3];
    const float* b_conv = (const float*)d_in[4];
    const float* gate   = (const float*)d_in[5];
    float* out = (float*)d_out;

    const size_t e_bytes = (size_t)BB * NOFF * HF * WF * sizeof(float);
    dim3 grid_mix(BB * 16, CCH / CHUNK);

    if (ws_size >= e_bytes) {
        float* E = (float*)d_ws;
        int n_e = BB * NOFF * HF * WF;
        evidence_kernel<<<(n_e + 255) / 256, 256, 0, stream>>>(smap, sdir, E);
        mix_kernel<<<grid_mix, 256, 0, stream>>>(rgb, E, w_conv, b_conv, gate, out);
    } else {
        mix_fused_kernel<<<grid_mix, 256, 0, stream>>>(
            rgb, smap, sdir, w_conv, b_conv, gate, out);
    }
}

// Round 3
// 60.156 us; speedup vs baseline: 1.0189x; 1.0189x over previous
//
#include <hip/hip_runtime.h>

#define HRES 1024
#define WRES 1024
#define HF   128
#define WF   128
#define NOFF 6
#define CCH  512
#define BB   4
#define CHUNK 32

typedef float vfloat4 __attribute__((ext_vector_type(4)));

// ---------------------------------------------------------------------------
// Kernel A: low-res evidence, one thread per (b, k, i, j).
// E[b,k,i,j] = sum_{r,c in 3x3} smap[b, 8i+3+floor(dy)+r, 8j+3+floor(dx)+c]
//              * wy[r] * wx[c],  wx = [0.5(1-fx), 0.5, 0.5 fx] etc., zero-pad.
// (Derivation: resize 1024->128 linear samples at 8i+3.5 = avg of rows 8i+3,
//  8i+4; composed with the constant-shift bilinear warp -> separable 3x3.)
// ---------------------------------------------------------------------------
__global__ void evidence_kernel(const float* __restrict__ smap,
                                const float* __restrict__ sdir,
                                float* __restrict__ E) {
    int t = blockIdx.x * blockDim.x + threadIdx.x;
    if (t >= BB * NOFF * HF * WF) return;
    int j = t & (WF - 1);
    int i = (t >> 7) & (HF - 1);
    int k = (t >> 14) % NOFF;
    int b = t / (NOFF << 14);

    const float offs[NOFF] = {12.f, 20.f, 30.f, 42.f, 55.f, 67.f};
    float dirx = sdir[b * 2 + 0];
    float diry = sdir[b * 2 + 1];
    float d  = offs[k];
    float dx = dirx * d;
    float dy = -diry * d;
    float fxf = floorf(dx), fyf = floorf(dy);
    float wx = dx - fxf,    wy = dy - fyf;

    int X0 = 8 * j + 3 + (int)fxf;
    int Y0 = 8 * i + 3 + (int)fyf;

    float wxv[3] = {0.5f * (1.f - wx), 0.5f, 0.5f * wx};
    float wyv[3] = {0.5f * (1.f - wy), 0.5f, 0.5f * wy};

    const float* img = smap + (size_t)b * HRES * WRES;
    float acc = 0.f;
#pragma unroll
    for (int r = 0; r < 3; ++r) {
        int y = Y0 + r;
        if ((unsigned)y < HRES) {
            float rowacc = 0.f;
#pragma unroll
            for (int c = 0; c < 3; ++c) {
                int x = X0 + c;
                float v = ((unsigned)x < WRES) ? img[(size_t)y * WRES + x] : 0.f;
                rowacc += v * wxv[c];
            }
            acc += rowacc * wyv[r];
        }
    }
    E[t] = acc;
}

// ---------------------------------------------------------------------------
// Kernel B: out[b,c,h,w] = rgb[b,c,h,w] + gate*(sum_k E[b,k,h,w]*w[c,k] + b[c])
// Block: 256 threads x 4 pixels (float4); grid (B*16 tiles, 16 channel chunks).
// rgb/out are pure streams (touched once) -> nontemporal so they don't evict
// E (1.5 MB, re-read by all 16 channel-chunk blocks) from L2.
// ---------------------------------------------------------------------------
__global__ __launch_bounds__(256) void mix_kernel(
        const float* __restrict__ rgb,
        const float* __restrict__ E,
        const float* __restrict__ w_conv,
        const float* __restrict__ b_conv,
        const float* __restrict__ gate,
        float* __restrict__ out) {
    __shared__ float s_w[CHUNK * NOFF];
    __shared__ float s_b[CHUNK];

    int tile = blockIdx.x;            // 0 .. B*16-1
    int b    = tile >> 4;
    int p    = (tile & 15) * 1024 + threadIdx.x * 4;   // pixel offset in hw-flat
    int c0   = blockIdx.y * CHUNK;
    float g  = gate[0];

    for (int idx = threadIdx.x; idx < CHUNK * NOFF; idx += blockDim.x)
        s_w[idx] = g * w_conv[(size_t)(c0 + idx / NOFF) * NOFF + idx % NOFF];
    for (int idx = threadIdx.x; idx < CHUNK; idx += blockDim.x)
        s_b[idx] = g * b_conv[c0 + idx];
    __syncthreads();

    vfloat4 e[NOFF];
#pragma unroll
    for (int k = 0; k < NOFF; ++k)
        e[k] = *reinterpret_cast<const vfloat4*>(
            E + (((size_t)(b * NOFF + k)) << 14) + p);

    const vfloat4* rgbp = reinterpret_cast<const vfloat4*>(
        rgb + (((size_t)(b * CCH + c0)) << 14) + p);
    vfloat4* outp = reinterpret_cast<vfloat4*>(
        out + (((size_t)(b * CCH + c0)) << 14) + p);
    const int stride4 = (1 << 14) / 4;   // channel stride in float4 units

#pragma unroll 4
    for (int c = 0; c < CHUNK; ++c) {
        float w0 = s_w[c * NOFF + 0], w1 = s_w[c * NOFF + 1];
        float w2 = s_w[c * NOFF + 2], w3 = s_w[c * NOFF + 3];
        float w4 = s_w[c * NOFF + 4], w5 = s_w[c * NOFF + 5];
        float bb = s_b[c];
        vfloat4 r = __builtin_nontemporal_load(rgbp + (size_t)c * stride4);
        vfloat4 o;
        o.x = r.x + bb + e[0].x * w0 + e[1].x * w1 + e[2].x * w2
                       + e[3].x * w3 + e[4].x * w4 + e[5].x * w5;
        o.y = r.y + bb + e[0].y * w0 + e[1].y * w1 + e[2].y * w2
                       + e[3].y * w3 + e[4].y * w4 + e[5].y * w5;
        o.z = r.z + bb + e[0].z * w0 + e[1].z * w1 + e[2].z * w2
                       + e[3].z * w3 + e[4].z * w4 + e[5].z * w5;
        o.w = r.w + bb + e[0].w * w0 + e[1].w * w1 + e[2].w * w2
                       + e[3].w * w3 + e[4].w * w4 + e[5].w * w5;
        __builtin_nontemporal_store(o, outp + (size_t)c * stride4);
    }
}

extern "C" void kernel_launch(void* const* d_in, const int* in_sizes, int n_in,
                              void* d_out, int out_size, void* d_ws, size_t ws_size,
                              hipStream_t stream) {
    const float* rgb    = (const float*)d_in[0];
    const float* smap   = (const float*)d_in[1];
    const float* sdir   = (const float*)d_in[2];
    const float* w_conv = (const float*)d_in[3];
    const float* b_conv = (const float*)d_in[4];
    const float* gate   = (const float*)d_in[5];
    float* out = (float*)d_out;

    float* E = (float*)d_ws;   // 1.5 MB << ws
    int n_e = BB * NOFF * HF * WF;
    evidence_kernel<<<(n_e + 255) / 256, 256, 0, stream>>>(smap, sdir, E);

    dim3 grid_mix(BB * 16, CCH / CHUNK);
    mix_kernel<<<grid_mix, 256, 0, stream>>>(rgb, E, w_conv, b_conv, gate, out);
}

// Round 4
// 58.599 us; speedup vs baseline: 1.0460x; 1.0266x over previous
//
#include <hip/hip_runtime.h>

#define HRES 1024
#define WRES 1024
#define HF   128
#define WF   128
#define NOFF 6
#define CCH  512
#define BB   4
#define CHUNK 32

typedef float vfloat4 __attribute__((ext_vector_type(4)));
typedef vfloat4 uvfloat4 __attribute__((aligned(4)));   // 4B-aligned vector load

// ---------------------------------------------------------------------------
// Kernel A: low-res evidence, one thread per (b, k, i, j).
// E[b,k,i,j] = sum_{r,c in 3x3} smap[b, 8i+3+floor(dy)+r, 8j+3+floor(dx)+c]
//              * wy[r] * wx[c],  wx = [0.5(1-fx), 0.5, 0.5 fx], zero-pad.
// Column taps are contiguous -> one dwordx4 per row (uses .x,.y,.z), with a
// guarded scalar path only when the 4-float window crosses the image edge.
// ---------------------------------------------------------------------------
__global__ void evidence_kernel(const float* __restrict__ smap,
                                const float* __restrict__ sdir,
                                float* __restrict__ E) {
    int t = blockIdx.x * blockDim.x + threadIdx.x;
    if (t >= BB * NOFF * HF * WF) return;
    int j = t & (WF - 1);
    int i = (t >> 7) & (HF - 1);
    int k = (t >> 14) % NOFF;
    int b = t / (NOFF << 14);

    const float offs[NOFF] = {12.f, 20.f, 30.f, 42.f, 55.f, 67.f};
    float dirx = sdir[b * 2 + 0];
    float diry = sdir[b * 2 + 1];
    float d  = offs[k];
    float dx = dirx * d;
    float dy = -diry * d;
    float fxf = floorf(dx), fyf = floorf(dy);
    float wx = dx - fxf,    wy = dy - fyf;

    int X0 = 8 * j + 3 + (int)fxf;
    int Y0 = 8 * i + 3 + (int)fyf;

    float wx0 = 0.5f * (1.f - wx), wx1 = 0.5f, wx2 = 0.5f * wx;
    float wyv[3] = {0.5f * (1.f - wy), 0.5f, 0.5f * wy};

    const float* img = smap + (size_t)b * HRES * WRES;
    bool fastx = (X0 >= 0) & (X0 + 3 < WRES);   // safe 16B window
    float acc = 0.f;
#pragma unroll
    for (int r = 0; r < 3; ++r) {
        int y = Y0 + r;
        if ((unsigned)y < HRES) {
            const float* rowp = img + (size_t)y * WRES;
            float s0, s1, s2;
            if (fastx) {
                vfloat4 v = *reinterpret_cast<const uvfloat4*>(rowp + X0);
                s0 = v.x; s1 = v.y; s2 = v.z;
            } else {
                s0 = ((unsigned)(X0 + 0) < WRES) ? rowp[X0 + 0] : 0.f;
                s1 = ((unsigned)(X0 + 1) < WRES) ? rowp[X0 + 1] : 0.f;
                s2 = ((unsigned)(X0 + 2) < WRES) ? rowp[X0 + 2] : 0.f;
            }
            acc += (s0 * wx0 + s1 * wx1 + s2 * wx2) * wyv[r];
        }
    }
    E[t] = acc;
}

// ---------------------------------------------------------------------------
// Kernel B: out[b,c,h,w] = rgb[b,c,h,w] + gate*(sum_k E[b,k,h,w]*w[c,k] + b[c])
// 256 thr x 4 px (float4); grid (B*16 pixel tiles, 16 channel chunks).
// 8-deep load batches: 8 channels' rgb loaded before any compute/store ->
// 8 outstanding 16B loads/wave; stores overlap the next batch's loads.
// ---------------------------------------------------------------------------
__global__ __launch_bounds__(256) void mix_kernel(
        const float* __restrict__ rgb,
        const float* __restrict__ E,
        const float* __restrict__ w_conv,
        const float* __restrict__ b_conv,
        const float* __restrict__ gate,
        float* __restrict__ out) {
    __shared__ float s_w[CHUNK * NOFF];
    __shared__ float s_b[CHUNK];

    int tile = blockIdx.x;            // 0 .. B*16-1
    int b    = tile >> 4;
    int p    = (tile & 15) * 1024 + threadIdx.x * 4;   // pixel offset in hw-flat
    int c0   = blockIdx.y * CHUNK;
    float g  = gate[0];

    for (int idx = threadIdx.x; idx < CHUNK * NOFF; idx += blockDim.x)
        s_w[idx] = g * w_conv[(size_t)(c0 + idx / NOFF) * NOFF + idx % NOFF];
    for (int idx = threadIdx.x; idx < CHUNK; idx += blockDim.x)
        s_b[idx] = g * b_conv[c0 + idx];
    __syncthreads();

    vfloat4 e[NOFF];
#pragma unroll
    for (int k = 0; k < NOFF; ++k)
        e[k] = *reinterpret_cast<const vfloat4*>(
            E + (((size_t)(b * NOFF + k)) << 14) + p);

    const vfloat4* rgbp = reinterpret_cast<const vfloat4*>(
        rgb + (((size_t)(b * CCH + c0)) << 14) + p);
    vfloat4* outp = reinterpret_cast<vfloat4*>(
        out + (((size_t)(b * CCH + c0)) << 14) + p);
    const int stride4 = (1 << 14) / 4;   // channel stride in float4 units

#pragma unroll
    for (int c8 = 0; c8 < CHUNK / 8; ++c8) {
        vfloat4 r[8];
#pragma unroll
        for (int u = 0; u < 8; ++u)
            r[u] = __builtin_nontemporal_load(
                rgbp + (size_t)(c8 * 8 + u) * stride4);
#pragma unroll
        for (int u = 0; u < 8; ++u) {
            int c = c8 * 8 + u;
            float w0 = s_w[c * NOFF + 0], w1 = s_w[c * NOFF + 1];
            float w2 = s_w[c * NOFF + 2], w3 = s_w[c * NOFF + 3];
            float w4 = s_w[c * NOFF + 4], w5 = s_w[c * NOFF + 5];
            float bb = s_b[c];
            vfloat4 o;
            o.x = r[u].x + bb + e[0].x * w0 + e[1].x * w1 + e[2].x * w2
                               + e[3].x * w3 + e[4].x * w4 + e[5].x * w5;
            o.y = r[u].y + bb + e[0].y * w0 + e[1].y * w1 + e[2].y * w2
                               + e[3].y * w3 + e[4].y * w4 + e[5].y * w5;
            o.z = r[u].z + bb + e[0].z * w0 + e[1].z * w1 + e[2].z * w2
                               + e[3].z * w3 + e[4].z * w4 + e[5].z * w5;
            o.w = r[u].w + bb + e[0].w * w0 + e[1].w * w1 + e[2].w * w2
                               + e[3].w * w3 + e[4].w * w4 + e[5].w * w5;
            __builtin_nontemporal_store(o, outp + (size_t)c * stride4);
        }
    }
}

extern "C" void kernel_launch(void* const* d_in, const int* in_sizes, int n_in,
                              void* d_out, int out_size, void* d_ws, size_t ws_size,
                              hipStream_t stream) {
    const float* rgb    = (const float*)d_in[0];
    const float* smap   = (const float*)d_in[1];
    const float* sdir   = (const float*)d_in[2];
    const float* w_conv = (const float*)d_in[3];
    const float* b_conv = (const float*)d_in[4];
    const float* gate   = (const float*)d_in[5];
    float* out = (float*)d_out;

    float* E = (float*)d_ws;   // 1.5 MB << ws
    int n_e = BB * NOFF * HF * WF;
    evidence_kernel<<<(n_e + 255) / 256, 256, 0, stream>>>(smap, sdir, E);

    dim3 grid_mix(BB * 16, CCH / CHUNK);
    mix_kernel<<<grid_mix, 256, 0, stream>>>(rgb, E, w_conv, b_conv, gate, out);
}